// Round 10
// baseline (814.133 us; speedup 1.0000x reference)
//
#include <hip/hip_runtime.h>
#include <math.h>

// Problem constants (fixed by the reference's setup_inputs)
#define NU 100000
#define NI 50000
#define NN 150000          // NU + NI
#define NNP 150528         // NN padded to 147*1024 for the scan
#define SCNB 147           // scan blocks (1024 elems each)
#define LNEPS 1e-5f
#define RSZ 8192           // histogram range size (32 KB LDS)
#define NR 19              // ranges: 19*8192 = 155648 >= NNP
#define BCH 16             // edge chunks

typedef short bfx8 __attribute__((ext_vector_type(8)));
typedef float f32x4 __attribute__((ext_vector_type(4)));
#define MFMA16(a, b, c) __builtin_amdgcn_mfma_f32_16x16x32_bf16(a, b, c, 0, 0, 0)

__device__ __forceinline__ unsigned short f2bf(float f) {
    unsigned u = __float_as_uint(f);
    unsigned r = u + 0x7FFFu + ((u >> 16) & 1u);   // RNE
    return (unsigned short)(r >> 16);
}

// ---------------------------------------------------------------------------
// S bitmap: sampled nodes.
// ---------------------------------------------------------------------------
__global__ __launch_bounds__(256) void k_markS(const int* __restrict__ users,
                                               const int* __restrict__ items,
                                               unsigned* __restrict__ bS, int nb) {
    int t = blockIdx.x * 256 + threadIdx.x;
    if (t < 2 * nb) {
        int node = (t < nb) ? users[t] : (NU + items[t - nb]);
        atomicOr(&bS[node >> 5], 1u << (node & 31));
    }
}

// ---------------------------------------------------------------------------
// k_hist: LDS-privatized range histograms, NO global atomics (flush = stores).
// grid (chunk b, range r, mode).  mode0: pdeg[b][*] over row + bR bitmap.
// mode1: pcnt[b][*] over col.
// ---------------------------------------------------------------------------
__global__ __launch_bounds__(256) void k_hist(const int* __restrict__ row,
                                              const int* __restrict__ col,
                                              const unsigned* __restrict__ bS,
                                              int* __restrict__ pdeg,
                                              int* __restrict__ pcnt,
                                              unsigned* __restrict__ bR,
                                              int E, int ech) {
    __shared__ int h[RSZ];
    __shared__ unsigned bb[RSZ / 32];
    int b = blockIdx.x, r = blockIdx.y, mode = blockIdx.z;
    int lo = r * RSZ;
    int lim = NNP - lo; if (lim > RSZ) lim = RSZ;
    int tid = threadIdx.x;
    for (int i = tid; i < RSZ; i += 256) h[i] = 0;
    if (mode == 0)
        for (int i = tid; i < RSZ / 32; i += 256) bb[i] = 0;
    __syncthreads();
    int e0 = b * ech, e1 = e0 + ech; if (e1 > E) e1 = E;
    if (mode == 0) {
        for (int e = e0 + tid; e < e1; e += 256) {
            int rr = row[e];
            unsigned idx = (unsigned)(rr - lo);
            if (idx < (unsigned)RSZ) {
                atomicAdd(&h[idx], 1);
                int c = col[e];
                if ((bS[c >> 5] >> (c & 31)) & 1u)
                    atomicOr(&bb[idx >> 5], 1u << (idx & 31));
            }
        }
    } else {
        for (int e = e0 + tid; e < e1; e += 256) {
            int c = col[e];
            unsigned idx = (unsigned)(c - lo);
            if (idx < (unsigned)RSZ) atomicAdd(&h[idx], 1);
        }
    }
    __syncthreads();
    int* dst = (mode == 0 ? pdeg : pcnt) + (size_t)b * NNP + lo;
    for (int i = tid; i < lim; i += 256) dst[i] = h[i];
    if (mode == 0) {
        int wlim = (lim + 31) >> 5;
        for (int i = tid; i < wlim; i += 256) {
            unsigned v = bb[i];
            if (v) atomicOr(&bR[(lo >> 5) + i], v);
        }
    }
}

// ---------------------------------------------------------------------------
// k_reduce: deg = sum_b pdeg -> dis; cnt = sum_b pcnt; pcnt <- per-chunk
// exclusive prefix (in place) for atomic-free placement.
// ---------------------------------------------------------------------------
__global__ __launch_bounds__(256) void k_reduce(const int* __restrict__ pdeg,
                                                int* __restrict__ pcnt,
                                                float* __restrict__ dis,
                                                int* __restrict__ cnt) {
    int i = blockIdx.x * 256 + threadIdx.x;
    if (i >= NNP) return;
    int d = 0;
#pragma unroll
    for (int b = 0; b < BCH; ++b) d += pdeg[(size_t)b * NNP + i];
    if (i < NN) dis[i] = rsqrtf((float)d);   // deg>0 guaranteed by self-loop
    int acc = 0;
#pragma unroll
    for (int b = 0; b < BCH; ++b) {
        int v = pcnt[(size_t)b * NNP + i];
        pcnt[(size_t)b * NNP + i] = acc;
        acc += v;
    }
    cnt[i] = acc;
}

// ---------------------------------------------------------------------------
// Exclusive scan of cnt[NNP] -> start[NNP+1]  (unfiltered)
// ---------------------------------------------------------------------------
__global__ __launch_bounds__(256) void k_scan1(const int* __restrict__ cnt,
                                               int* __restrict__ bsum) {
    __shared__ int sh[256];
    int b = blockIdx.x, t = threadIdx.x;
    int4 v = ((const int4*)cnt)[b * 256 + t];
    sh[t] = v.x + v.y + v.z + v.w;
    __syncthreads();
    for (int off = 128; off >= 1; off >>= 1) {
        if (t < off) sh[t] += sh[t + off];
        __syncthreads();
    }
    if (t == 0) bsum[b] = sh[0];
}

__global__ __launch_bounds__(256) void k_scan2(int* __restrict__ bsum, int nblk) {
    __shared__ int sh[256];
    int t = threadIdx.x;
    int v = (t < nblk) ? bsum[t] : 0;
    sh[t] = v;
    __syncthreads();
    for (int off = 1; off < 256; off <<= 1) {
        int add = (t >= off) ? sh[t - off] : 0;
        __syncthreads();
        sh[t] += add;
        __syncthreads();
    }
    if (t < nblk) bsum[t] = sh[t] - v;   // exclusive
}

__global__ __launch_bounds__(256) void k_scan3(const int* __restrict__ cnt,
                                               const int* __restrict__ bsum,
                                               int* __restrict__ start) {
    __shared__ int sh[257];
    int b = blockIdx.x, t = threadIdx.x;
    int4 v = ((const int4*)cnt)[b * 256 + t];
    int s = v.x + v.y + v.z + v.w;
    sh[t + 1] = s;
    if (t == 0) sh[0] = 0;
    __syncthreads();
    for (int off = 1; off < 256; off <<= 1) {
        int add = sh[t + 1] + ((t + 1 > off) ? sh[t + 1 - off] : 0);
        __syncthreads();
        sh[t + 1] = add;
        __syncthreads();
    }
    int base = bsum[b] + sh[t];
    int i0 = b * 1024 + t * 4;
    start[i0 + 0] = base;  base += v.x;
    start[i0 + 1] = base;  base += v.y;
    start[i0 + 2] = base;  base += v.z;
    start[i0 + 3] = base;
    if (b == SCNB - 1 && t == 255) start[NNP] = base + v.w;
}

// ---------------------------------------------------------------------------
// k_placeH: atomic-free placement.  Block (chunk b, range r): LDS cursors
// seeded with start[c] + pre[b][c]; slots via LDS atomicAdd only.
// ---------------------------------------------------------------------------
__global__ __launch_bounds__(256) void k_placeH(const int* __restrict__ row,
                                                const int* __restrict__ col,
                                                const int* __restrict__ start,
                                                const int* __restrict__ pre,
                                                int* __restrict__ el,
                                                int E, int ech) {
    __shared__ int cur[RSZ];
    int b = blockIdx.x, r = blockIdx.y;
    int lo = r * RSZ;
    int lim = NNP - lo; if (lim > RSZ) lim = RSZ;
    int tid = threadIdx.x;
    const int* prb = pre + (size_t)b * NNP + lo;
    for (int i = tid; i < lim; i += 256) cur[i] = start[lo + i] + prb[i];
    __syncthreads();
    int e0 = b * ech, e1 = e0 + ech; if (e1 > E) e1 = E;
    for (int e = e0 + tid; e < e1; e += 256) {
        int c = col[e];
        unsigned idx = (unsigned)(c - lo);
        if (idx < (unsigned)lim) {
            int slot = atomicAdd(&cur[idx], 1);
            el[slot] = row[e];
        }
    }
}

// ---------------------------------------------------------------------------
// gather1: g1[c] = dis[c] * sum dis[r]*x_raw[r];  sdeg[c] = dis[c]*sum dis[r].
// One wave per col; only cols in R (bitmap).  4-way ILP.
// ---------------------------------------------------------------------------
__global__ __launch_bounds__(256) void k_gather1(const int* __restrict__ el,
                                                 const int* __restrict__ start,
                                                 const float* __restrict__ dis,
                                                 const unsigned* __restrict__ filt,
                                                 const float* __restrict__ ut,
                                                 const float* __restrict__ itb,
                                                 float* __restrict__ g1,
                                                 float* __restrict__ sdeg) {
    int wid = (blockIdx.x * 256 + threadIdx.x) >> 6;
    int j = threadIdx.x & 63;
    if (wid >= NN) return;
    if (!((filt[wid >> 5] >> (wid & 31)) & 1u)) return;
    int s = start[wid], e = start[wid + 1];
    float a0 = 0.f, a1 = 0.f, a2 = 0.f, a3 = 0.f, sn = 0.f;
    int i = s;
    for (; i + 3 < e; i += 4) {
        int r0 = el[i], r1 = el[i + 1], r2 = el[i + 2], r3 = el[i + 3];
        float d0 = dis[r0], d1 = dis[r1], d2 = dis[r2], d3 = dis[r3];
        const float* p0 = (r0 < NU) ? ut + (size_t)r0 * 64 : itb + (size_t)(r0 - NU) * 64;
        const float* p1 = (r1 < NU) ? ut + (size_t)r1 * 64 : itb + (size_t)(r1 - NU) * 64;
        const float* p2 = (r2 < NU) ? ut + (size_t)r2 * 64 : itb + (size_t)(r2 - NU) * 64;
        const float* p3 = (r3 < NU) ? ut + (size_t)r3 * 64 : itb + (size_t)(r3 - NU) * 64;
        a0 = fmaf(d0, p0[j], a0);
        a1 = fmaf(d1, p1[j], a1);
        a2 = fmaf(d2, p2[j], a2);
        a3 = fmaf(d3, p3[j], a3);
        sn += (d0 + d1) + (d2 + d3);
    }
    for (; i < e; ++i) {
        int r0 = el[i];
        float d0 = dis[r0];
        const float* p0 = (r0 < NU) ? ut + (size_t)r0 * 64 : itb + (size_t)(r0 - NU) * 64;
        a0 = fmaf(d0, p0[j], a0);
        sn += d0;
    }
    float dc = dis[wid];
    g1[(size_t)wid * 64 + j] = dc * ((a0 + a1) + (a2 + a3));
    if (j == 0) sdeg[wid] = dc * sn;
}

// ---------------------------------------------------------------------------
// gather2: gg[c] = dis[c]*sum dis[r]*g1[r];  s2[c] = dis[c]*sum dis[r]*sdeg[r].
// cols in S.
// ---------------------------------------------------------------------------
__global__ __launch_bounds__(256) void k_gather2(const int* __restrict__ el,
                                                 const int* __restrict__ start,
                                                 const float* __restrict__ dis,
                                                 const unsigned* __restrict__ bS,
                                                 const float* __restrict__ g1,
                                                 const float* __restrict__ sdeg,
                                                 float* __restrict__ gg,
                                                 float* __restrict__ s2) {
    int wid = (blockIdx.x * 256 + threadIdx.x) >> 6;
    int j = threadIdx.x & 63;
    if (wid >= NN) return;
    if (!((bS[wid >> 5] >> (wid & 31)) & 1u)) return;
    int s = start[wid], e = start[wid + 1];
    float a0 = 0.f, a1 = 0.f, a2 = 0.f, a3 = 0.f, sa = 0.f;
    int i = s;
    for (; i + 3 < e; i += 4) {
        int r0 = el[i], r1 = el[i + 1], r2 = el[i + 2], r3 = el[i + 3];
        float d0 = dis[r0], d1 = dis[r1], d2 = dis[r2], d3 = dis[r3];
        a0 = fmaf(d0, g1[(size_t)r0 * 64 + j], a0);
        a1 = fmaf(d1, g1[(size_t)r1 * 64 + j], a1);
        a2 = fmaf(d2, g1[(size_t)r2 * 64 + j], a2);
        a3 = fmaf(d3, g1[(size_t)r3 * 64 + j], a3);
        sa = fmaf(d0, sdeg[r0], sa);
        sa = fmaf(d1, sdeg[r1], sa);
        sa = fmaf(d2, sdeg[r2], sa);
        sa = fmaf(d3, sdeg[r3], sa);
    }
    for (; i < e; ++i) {
        int r0 = el[i];
        float d0 = dis[r0];
        a0 = fmaf(d0, g1[(size_t)r0 * 64 + j], a0);
        sa = fmaf(d0, sdeg[r0], sa);
    }
    float dc = dis[wid];
    gg[(size_t)wid * 64 + j] = dc * ((a0 + a1) + (a2 + a3));
    if (j == 0) s2[wid] = dc * sa;
}

// ---------------------------------------------------------------------------
// k_fuse: W_va[l] = Wv[l] @ Wo[l];  b_va[l] = bv[l] @ Wo[l] + bo[l]
// ---------------------------------------------------------------------------
__global__ __launch_bounds__(256) void k_fuse(const float* __restrict__ qkvW,
                                              const float* __restrict__ qkvB,
                                              const float* __restrict__ outW,
                                              const float* __restrict__ outB,
                                              float* __restrict__ Wva,
                                              float* __restrict__ bva) {
    int l = blockIdx.x;
    __shared__ float wo[4096];
    int tid = threadIdx.x, j = tid & 63, kq = tid >> 6;
    for (int i = tid; i < 4096; i += 256) wo[i] = outW[l * 4096 + i];
    __syncthreads();
    for (int kk = 0; kk < 16; ++kk) {
        int k = kq * 16 + kk;
        float acc = 0.f;
        for (int m = 0; m < 64; ++m)
            acc = fmaf(qkvW[(size_t)l * 64 * 192 + k * 192 + 128 + m],
                       wo[m * 64 + j], acc);
        Wva[l * 4096 + k * 64 + j] = acc;
    }
    if (tid < 64) {
        float acc = outB[l * 64 + j];
        for (int m = 0; m < 64; ++m)
            acc = fmaf(qkvB[l * 192 + 128 + m], wo[m * 64 + j], acc);
        bva[l * 64 + j] = acc;
    }
}

// ---------------------------------------------------------------------------
// k_fuse2: Wff = W0@W1@corrW; bff = [b0@W1@corrW, b1@corrW, corrB]
// ---------------------------------------------------------------------------
__global__ __launch_bounds__(256) void k_fuse2(const float* __restrict__ glW,
                                               const float* __restrict__ glB,
                                               const float* __restrict__ corrW,
                                               const float* __restrict__ corrB,
                                               float* __restrict__ Wff,
                                               float* __restrict__ bff) {
    __shared__ float A[4096];   // W1
    __shared__ float B[4096];   // corrW
    __shared__ float T[4096];   // W0@W1
    __shared__ float vec[64];
    int tid = threadIdx.x, j = tid & 63, kq = tid >> 6;
    for (int i = tid; i < 4096; i += 256) { A[i] = glW[4096 + i]; B[i] = corrW[i]; }
    __syncthreads();
    for (int kk = 0; kk < 16; ++kk) {
        int k = kq * 16 + kk;
        float acc = 0.f;
        for (int m = 0; m < 64; ++m) acc = fmaf(glW[k * 64 + m], A[m * 64 + j], acc);
        T[k * 64 + j] = acc;
    }
    if (tid < 64) {
        float v = 0.f;
        for (int m = 0; m < 64; ++m) v = fmaf(glB[m], A[m * 64 + tid], v);
        vec[tid] = v;
    }
    __syncthreads();
    for (int kk = 0; kk < 16; ++kk) {
        int k = kq * 16 + kk;
        float acc = 0.f;
        for (int m = 0; m < 64; ++m) acc = fmaf(T[k * 64 + m], B[m * 64 + j], acc);
        Wff[k * 64 + j] = acc;
    }
    if (kq == 0) {
        float a = 0.f;
        for (int m = 0; m < 64; ++m) a = fmaf(vec[m], B[m * 64 + j], a);
        bff[j] = a;
    } else if (kq == 1) {
        float a = 0.f;
        for (int m = 0; m < 64; ++m) a = fmaf(glB[64 + m], B[m * 64 + j], a);
        bff[64 + j] = a;
    } else if (kq == 2) {
        bff[128 + j] = corrB[j];
    }
}

// ---------------------------------------------------------------------------
// k_wprep: transpose+convert FFN weights to bf16.
// ---------------------------------------------------------------------------
__global__ __launch_bounds__(256) void k_wprep(const float* __restrict__ ff1W,
                                               const float* __restrict__ ff2W,
                                               unsigned short* __restrict__ Wt1,
                                               unsigned short* __restrict__ Wt2) {
    __shared__ float sh[64][65];
    int b = blockIdx.x;          // 0..127
    int l = b >> 6, rem = b & 63;
    int mat = rem >> 5, tile = rem & 31;
    const float* src; unsigned short* dst; int C, R, r0, c0;
    if (mat == 0) { src = ff1W + (size_t)l * 64 * 2048; dst = Wt1 + (size_t)l * 2048 * 64;
                    R = 64; C = 2048; r0 = 0; c0 = tile * 64; }
    else          { src = ff2W + (size_t)l * 2048 * 64; dst = Wt2 + (size_t)l * 64 * 2048;
                    R = 2048; C = 64; r0 = tile * 64; c0 = 0; }
    int tid = threadIdx.x;
    for (int it = 0; it < 16; ++it) {
        int idx = it * 256 + tid;
        int lr = idx >> 6, lc = idx & 63;
        sh[lr][lc] = src[(size_t)(r0 + lr) * C + (c0 + lc)];
    }
    __syncthreads();
    for (int it = 0; it < 16; ++it) {
        int idx = it * 256 + tid;
        int lc = idx >> 6, lr = idx & 63;
        dst[(size_t)(c0 + lc) * R + (r0 + lr)] = f2bf(sh[lr][lc]);
    }
}

// ---------------------------------------------------------------------------
// k_proj: Cb[b] = gg[node]@Wff + s2[node]*bff1 + sdeg[node]*bff2 + corrB
// ---------------------------------------------------------------------------
__global__ __launch_bounds__(256) void k_proj(const float* __restrict__ gg,
                                              const float* __restrict__ sdeg,
                                              const float* __restrict__ s2,
                                              const int* __restrict__ users,
                                              const int* __restrict__ items,
                                              const float* __restrict__ Wff,
                                              const float* __restrict__ bff,
                                              float* __restrict__ Cb, int nb) {
    __shared__ float Ws[4096];
    __shared__ float xsh[16][64];
    __shared__ float ssh[16][2];
    int tid = threadIdx.x, j = tid & 63, rq = tid >> 6;
    for (int i = tid; i < 4096; i += 256) Ws[i] = Wff[i];
    int r0 = blockIdx.x * 16;
    for (int i = tid; i < 1024; i += 256) {
        int b = r0 + (i >> 6);
        int node = (b < nb) ? users[b] : (NU + items[b - nb]);
        xsh[i >> 6][i & 63] = gg[(size_t)node * 64 + (i & 63)];
    }
    if (tid < 16) {
        int b = r0 + tid;
        int node = (b < nb) ? users[b] : (NU + items[b - nb]);
        ssh[tid][0] = s2[node];
        ssh[tid][1] = sdeg[node];
    }
    __syncthreads();
    float b1j = bff[j], b2j = bff[64 + j], cbj = bff[128 + j];
    float acc[4];
#pragma unroll
    for (int i = 0; i < 4; ++i) acc[i] = cbj;
    for (int k = 0; k < 64; ++k) {
        float w = Ws[k * 64 + j];
#pragma unroll
        for (int i = 0; i < 4; ++i) acc[i] = fmaf(xsh[rq + 4 * i][k], w, acc[i]);
    }
#pragma unroll
    for (int i = 0; i < 4; ++i) {
        int r = rq + 4 * i;
        Cb[(size_t)(r0 + r) * 64 + j] = acc[i] + ssh[r][0] * b1j + ssh[r][1] * b2j;
    }
}

// ---------------------------------------------------------------------------
// k_attn: x = LN1(x + x @ W_va + b_va).  Writes fp32 Cb and bf16 xb.
// ---------------------------------------------------------------------------
__global__ __launch_bounds__(256) void k_attn(float* __restrict__ Cb,
                                              unsigned short* __restrict__ xb,
                                              const float* __restrict__ Wva,
                                              const float* __restrict__ bva,
                                              const float* __restrict__ g,
                                              const float* __restrict__ bt,
                                              int layer) {
    __shared__ float Ws[4096];
    __shared__ float xs[16][64];
    int tid = threadIdx.x, j = tid & 63, rq = tid >> 6;
    const float* wv = Wva + layer * 4096;
    for (int i = tid; i < 4096; i += 256) Ws[i] = wv[i];
    int row0 = blockIdx.x * 16;
    for (int i = tid; i < 1024; i += 256)
        xs[i >> 6][i & 63] = Cb[(size_t)(row0 + (i >> 6)) * 64 + (i & 63)];
    __syncthreads();
    float bv = bva[layer * 64 + j];
    float gg = g[layer * 64 + j], bb = bt[layer * 64 + j];
    float acc[4];
#pragma unroll
    for (int i = 0; i < 4; ++i) acc[i] = bv;
    for (int k = 0; k < 64; ++k) {
        float w = Ws[k * 64 + j];
#pragma unroll
        for (int i = 0; i < 4; ++i) acc[i] = fmaf(xs[rq * 4 + i][k], w, acc[i]);
    }
#pragma unroll
    for (int i = 0; i < 4; ++i) {
        int r = rq * 4 + i;
        float xv = xs[r][j] + acc[i];
        float s = xv;
#pragma unroll
        for (int o = 32; o >= 1; o >>= 1) s += __shfl_xor(s, o, 64);
        float m = s * (1.0f / 64.0f);
        float d = xv - m;
        float s2v = d * d;
#pragma unroll
        for (int o = 32; o >= 1; o >>= 1) s2v += __shfl_xor(s2v, o, 64);
        float xn = d * rsqrtf(s2v * (1.0f / 64.0f) + LNEPS) * gg + bb;
        Cb[(size_t)(row0 + r) * 64 + j] = xn;
        xb[(size_t)(row0 + r) * 64 + j] = f2bf(xn);
    }
}

// ---------------------------------------------------------------------------
// k_ffnm: full FFN via MFMA + fused residual + LN2.  (8 iters x 2 chunks,
// double-buffered ts, prefetched W2 frags)
// ---------------------------------------------------------------------------
__global__ __launch_bounds__(512) void k_ffnm(float* __restrict__ Cb,
                                              const unsigned short* __restrict__ xb,
                                              const unsigned short* __restrict__ Wt1,
                                              const unsigned short* __restrict__ Wt2,
                                              const float* __restrict__ ff1B,
                                              const float* __restrict__ ff2B,
                                              const float* __restrict__ g2,
                                              const float* __restrict__ b2t,
                                              int layer) {
    __shared__ short ts[2][32 * 128];   // bf16 t tiles, XOR-swizzled (16KB)
    __shared__ float ys[32 * 64];       // fp32 y (8KB)
    const unsigned short* w1 = Wt1 + (size_t)layer * 2048 * 64;
    const unsigned short* w2 = Wt2 + (size_t)layer * 64 * 2048;
    const float* b1 = ff1B + layer * 2048;
    int tid = threadIdx.x;
    int lane = tid & 63, wv = tid >> 6;
    int g = lane >> 4, r16 = lane & 15;
    int row0 = blockIdx.x * 32;
    int nt2 = wv & 3, mh = wv >> 2;

    bfx8 ax[2][2];
#pragma unroll
    for (int mt = 0; mt < 2; ++mt)
#pragma unroll
        for (int ks = 0; ks < 2; ++ks)
            ax[mt][ks] = *(const bfx8*)(xb + ((size_t)(row0 + 16 * mt + r16)) * 64
                                        + 32 * ks + 8 * g);

    f32x4 yfA = {0.f, 0.f, 0.f, 0.f}, yfB = {0.f, 0.f, 0.f, 0.f};
    int col = wv * 16 + r16;
    int trow = 16 * mh + r16;

    for (int hc2 = 0; hc2 < 8; ++hc2) {
        bfx8 w2f[2][4];
#pragma unroll
        for (int sub = 0; sub < 2; ++sub)
#pragma unroll
            for (int ks2 = 0; ks2 < 4; ++ks2)
                w2f[sub][ks2] = *(const bfx8*)(w2 + ((size_t)(16 * nt2 + r16)) * 2048
                                               + (hc2 * 2 + sub) * 128
                                               + 32 * ks2 + 8 * g);
#pragma unroll
        for (int sub = 0; sub < 2; ++sub) {
            int h = (hc2 * 2 + sub) * 128 + wv * 16 + r16;
            float b1v = b1[h];
            f32x4 tf0 = {b1v, b1v, b1v, b1v}, tf1 = tf0;
#pragma unroll
            for (int ks = 0; ks < 2; ++ks) {
                bfx8 bw = *(const bfx8*)(w1 + (size_t)h * 64 + 32 * ks + 8 * g);
                tf0 = MFMA16(ax[0][ks], bw, tf0);
                tf1 = MFMA16(ax[1][ks], bw, tf1);
            }
#pragma unroll
            for (int r = 0; r < 4; ++r) {
                int rowA = 4 * g + r, rowB = 16 + 4 * g + r;
                int offA = (rowA * 256 + col * 2) ^ ((rowA & 7) << 4);
                int offB = (rowB * 256 + col * 2) ^ ((rowB & 7) << 4);
                *(short*)((char*)ts[sub] + offA) = (short)f2bf(fmaxf(tf0[r], 0.f));
                *(short*)((char*)ts[sub] + offB) = (short)f2bf(fmaxf(tf1[r], 0.f));
            }
        }
        __syncthreads();
#pragma unroll
        for (int sub = 0; sub < 2; ++sub)
#pragma unroll
            for (int ks2 = 0; ks2 < 4; ++ks2) {
                int kl = 32 * ks2 + 8 * g;
                int off2 = (trow * 256 + kl * 2) ^ ((trow & 7) << 4);
                bfx8 ta = *(const bfx8*)((char*)ts[sub] + off2);
                if (ks2 & 1) yfB = MFMA16(ta, w2f[sub][ks2], yfB);
                else         yfA = MFMA16(ta, w2f[sub][ks2], yfA);
            }
        __syncthreads();
    }
#pragma unroll
    for (int r = 0; r < 4; ++r)
        ys[(16 * mh + 4 * g + r) * 64 + 16 * nt2 + r16] = yfA[r] + yfB[r];
    __syncthreads();
    float b2 = ff2B[layer * 64 + lane];
    float gg = g2[layer * 64 + lane], bb = b2t[layer * 64 + lane];
#pragma unroll
    for (int i = 0; i < 4; ++i) {
        int r = wv * 4 + i;
        float xv = Cb[(size_t)(row0 + r) * 64 + lane] + ys[r * 64 + lane] + b2;
        float s = xv;
#pragma unroll
        for (int o = 32; o >= 1; o >>= 1) s += __shfl_xor(s, o, 64);
        float m = s * (1.0f / 64.0f);
        float d = xv - m;
        float s2v = d * d;
#pragma unroll
        for (int o = 32; o >= 1; o >>= 1) s2v += __shfl_xor(s2v, o, 64);
        float xn = d * rsqrtf(s2v * (1.0f / 64.0f) + LNEPS) * gg + bb;
        Cb[(size_t)(row0 + r) * 64 + lane] = xn;
    }
}

// out[b] = dot(user_row b, item_row nb+b); quarter-wave per b.
__global__ __launch_bounds__(256) void k_dot(const float* __restrict__ Cb,
                                             float* __restrict__ out, int nb) {
    int t = blockIdx.x * 256 + threadIdx.x;
    int b = t >> 4;
    if (b >= nb) return;
    int q = (t & 15) * 4;
    const float4 u = *reinterpret_cast<const float4*>(Cb + (size_t)b * 64 + q);
    const float4 v = *reinterpret_cast<const float4*>(Cb + (size_t)(nb + b) * 64 + q);
    float s = u.x * v.x + u.y * v.y + u.z * v.z + u.w * v.w;
#pragma unroll
    for (int o = 8; o >= 1; o >>= 1) s += __shfl_xor(s, o, 16);
    if ((t & 15) == 0) out[b] = s;
}

extern "C" void kernel_launch(void* const* d_in, const int* in_sizes, int n_in,
                              void* d_out, int out_size, void* d_ws, size_t ws_size,
                              hipStream_t stream) {
    const int* users = (const int*)d_in[0];
    const int* items = (const int*)d_in[1];
    const int* ei    = (const int*)d_in[2];
    const float* ut  = (const float*)d_in[3];
    const float* itb = (const float*)d_in[4];
    const float* glW = (const float*)d_in[5];
    const float* glB = (const float*)d_in[6];
    const float* corrW = (const float*)d_in[7];
    const float* corrB = (const float*)d_in[8];
    const float* qkvW = (const float*)d_in[9];
    const float* qkvB = (const float*)d_in[10];
    const float* outW = (const float*)d_in[11];
    const float* outB = (const float*)d_in[12];
    const float* ff1W = (const float*)d_in[13];
    const float* ff1B = (const float*)d_in[14];
    const float* ff2W = (const float*)d_in[15];
    const float* ff2B = (const float*)d_in[16];
    const float* ln1g = (const float*)d_in[17];
    const float* ln1b = (const float*)d_in[18];
    const float* ln2g = (const float*)d_in[19];
    const float* ln2b = (const float*)d_in[20];

    const int E  = in_sizes[2] / 2;      // 1,750,000
    const int nb = in_sizes[0];          // 4096
    const int nrows = 2 * nb;            // 8192
    const int ech = (E + BCH - 1) / BCH;
    const int* rowp = ei;
    const int* colp = ei + E;

    // workspace carve-up (~92 MB)
    char* w = (char*)d_ws;
    size_t off = 0;
    auto alloc = [&](size_t bytes) {
        char* p = w + off;
        off += (bytes + 255) & ~(size_t)255;
        return p;
    };
    // zeroed region: bS, bR bitmaps only
    size_t zero0 = off;
    unsigned* bS    = (unsigned*)alloc((NNP / 32) * 4);
    unsigned* bR    = (unsigned*)alloc((NNP / 32) * 4);
    size_t zlen = off - zero0;
    float*    dis   = (float*)alloc((size_t)NN * 4);
    int*      cnt   = (int*)alloc((size_t)NNP * 4);
    int*      start = (int*)alloc((size_t)(NNP + 1) * 4);
    int*      bsum  = (int*)alloc((size_t)SCNB * 4);
    int*      el    = (int*)alloc((size_t)E * 4);
    float*    bufA  = (float*)alloc((size_t)NN * 64 * 4);   // g1 (38.4 MB)
    float*    bufB  = (float*)alloc((size_t)NN * 64 * 4);   // gg
    float*    sdeg  = (float*)alloc((size_t)NN * 4);
    float*    s2    = (float*)alloc((size_t)NN * 4);
    float*    cb    = (float*)alloc((size_t)nrows * 64 * 4);
    float*    Wva   = (float*)alloc(2 * 4096 * 4);
    float*    bva   = (float*)alloc(2 * 64 * 4);
    float*    Wff   = (float*)alloc(4096 * 4);
    float*    bff   = (float*)alloc(192 * 4);
    unsigned short* xbb = (unsigned short*)alloc((size_t)nrows * 64 * 2);
    unsigned short* Wt1 = (unsigned short*)alloc((size_t)2 * 2048 * 64 * 2);
    unsigned short* Wt2 = (unsigned short*)alloc((size_t)2 * 64 * 2048 * 2);
    float*    outp  = (float*)d_out;
    // histogram partials overlay bufA (dead until k_gather1):
    // pdeg[BCH][NNP] + pcnt[BCH][NNP] = 19.3 MB < 38.4 MB
    int* pdeg = (int*)bufA;
    int* pcnt = pdeg + (size_t)BCH * NNP;

    hipMemsetAsync(w + zero0, 0, zlen, stream);

    // --- CSR build: LDS-privatized histograms, no hot global atomics ---
    k_markS<<<(2 * nb + 255) / 256, 256, 0, stream>>>(users, items, bS, nb);
    dim3 hgrid(BCH, NR, 2);
    k_hist<<<hgrid, 256, 0, stream>>>(rowp, colp, bS, pdeg, pcnt, bR, E, ech);
    k_reduce<<<NNP / 256, 256, 0, stream>>>(pdeg, pcnt, dis, cnt);
    k_scan1<<<SCNB, 256, 0, stream>>>(cnt, bsum);
    k_scan2<<<1, 256, 0, stream>>>(bsum, SCNB);
    k_scan3<<<SCNB, 256, 0, stream>>>(cnt, bsum, start);
    dim3 pgrid(BCH, NR);
    k_placeH<<<pgrid, 256, 0, stream>>>(rowp, colp, start, pcnt, el, E, ech);
    k_fuse<<<2, 256, 0, stream>>>(qkvW, qkvB, outW, outB, Wva, bva);
    k_fuse2<<<1, 256, 0, stream>>>(glW, glB, corrW, corrB, Wff, bff);
    k_wprep<<<128, 256, 0, stream>>>(ff1W, ff2W, Wt1, Wt2);

    int agb = (NN + 3) / 4;    // 4 waves/block, 1 wave per col

    // commuted GCN: gather raw tables (R cols), gather again (S cols),
    // then one fused 8K-row projection
    k_gather1<<<agb, 256, 0, stream>>>(el, start, dis, bR, ut, itb, bufA, sdeg);
    k_gather2<<<agb, 256, 0, stream>>>(el, start, dis, bS, bufA, sdeg, bufB, s2);
    k_proj<<<(nrows + 15) / 16, 256, 0, stream>>>(bufB, sdeg, s2, users, items,
                                                  Wff, bff, cb, nb);

    // transformer: per layer  attn+LN1 (emits bf16 x) -> MFMA FFN + LN2
    for (int l = 0; l < 2; ++l) {
        k_attn<<<nrows / 16, 256, 0, stream>>>(cb, xbb, Wva, bva, ln1g, ln1b, l);
        k_ffnm<<<nrows / 32, 512, 0, stream>>>(cb, xbb, Wt1, Wt2, ff1B, ff2B,
                                               ln2g, ln2b, l);
    }
    k_dot<<<(nb * 16 + 255) / 256, 256, 0, stream>>>(cb, outp, nb);
}

// Round 11
// 482.815 us; speedup vs baseline: 1.6862x; 1.6862x over previous
//
#include <hip/hip_runtime.h>
#include <math.h>

// Problem constants (fixed by the reference's setup_inputs)
#define NU 100000
#define NI 50000
#define NN 150000          // NU + NI
#define NNP 150528         // NN padded to 147*1024 for the scan
#define SCNB 147           // scan blocks (1024 elems each)
#define LNEPS 1e-5f

typedef short bfx8 __attribute__((ext_vector_type(8)));
typedef float f32x4 __attribute__((ext_vector_type(4)));
#define MFMA16(a, b, c) __builtin_amdgcn_mfma_f32_16x16x32_bf16(a, b, c, 0, 0, 0)

__device__ __forceinline__ unsigned short f2bf(float f) {
    unsigned u = __float_as_uint(f);
    unsigned r = u + 0x7FFFu + ((u >> 16) & 1u);   // RNE
    return (unsigned short)(r >> 16);
}

// ---------------------------------------------------------------------------
// S bitmap: sampled nodes.
// ---------------------------------------------------------------------------
__global__ __launch_bounds__(256) void k_markS(const int* __restrict__ users,
                                               const int* __restrict__ items,
                                               unsigned* __restrict__ bS, int nb) {
    int t = blockIdx.x * 256 + threadIdx.x;
    if (t < 2 * nb) {
        int node = (t < nb) ? users[t] : (NU + items[t - nb]);
        atomicOr(&bS[node >> 5], 1u << (node & 31));
    }
}

// deg[row]++ (int) + bR mark (test-first: stale "set" is monotonic-safe).
__global__ __launch_bounds__(256) void k_pre1(const int* __restrict__ row,
                                              const int* __restrict__ col,
                                              const unsigned* __restrict__ bS,
                                              int* __restrict__ deg,
                                              unsigned* bR, int E) {
    int e = blockIdx.x * 256 + threadIdx.x;
    if (e >= E) return;
    int r = row[e];
    atomicAdd(&deg[r], 1);
    int c = col[e];
    if ((bS[c >> 5] >> (c & 31)) & 1u) {
        unsigned m = 1u << (r & 31);
        if (!(bR[r >> 5] & m)) atomicOr(&bR[r >> 5], m);
    }
}

__global__ __launch_bounds__(256) void k_dis(const int* __restrict__ deg,
                                             float* __restrict__ dis) {
    int i = blockIdx.x * 256 + threadIdx.x;
    if (i < NN) dis[i] = rsqrtf((float)deg[i]);
}

// count edges per col, only for cols in R
__global__ __launch_bounds__(256) void k_cnt(const int* __restrict__ col,
                                             const unsigned* __restrict__ bR,
                                             int* __restrict__ cnt, int E) {
    int e = blockIdx.x * 256 + threadIdx.x;
    if (e >= E) return;
    int c = col[e];
    if ((bR[c >> 5] >> (c & 31)) & 1u) atomicAdd(&cnt[c], 1);
}

// ---------------------------------------------------------------------------
// Exclusive scan of cnt[NNP] -> start[NNP+1]
// ---------------------------------------------------------------------------
__global__ __launch_bounds__(256) void k_scan1(const int* __restrict__ cnt,
                                               int* __restrict__ bsum) {
    __shared__ int sh[256];
    int b = blockIdx.x, t = threadIdx.x;
    int4 v = ((const int4*)cnt)[b * 256 + t];
    sh[t] = v.x + v.y + v.z + v.w;
    __syncthreads();
    for (int off = 128; off >= 1; off >>= 1) {
        if (t < off) sh[t] += sh[t + off];
        __syncthreads();
    }
    if (t == 0) bsum[b] = sh[0];
}

__global__ __launch_bounds__(256) void k_scan2(int* __restrict__ bsum, int nblk) {
    __shared__ int sh[256];
    int t = threadIdx.x;
    int v = (t < nblk) ? bsum[t] : 0;
    sh[t] = v;
    __syncthreads();
    for (int off = 1; off < 256; off <<= 1) {
        int add = (t >= off) ? sh[t - off] : 0;
        __syncthreads();
        sh[t] += add;
        __syncthreads();
    }
    if (t < nblk) bsum[t] = sh[t] - v;   // exclusive
}

__global__ __launch_bounds__(256) void k_scan3(const int* __restrict__ cnt,
                                               const int* __restrict__ bsum,
                                               int* __restrict__ start) {
    __shared__ int sh[257];
    int b = blockIdx.x, t = threadIdx.x;
    int4 v = ((const int4*)cnt)[b * 256 + t];
    int s = v.x + v.y + v.z + v.w;
    sh[t + 1] = s;
    if (t == 0) sh[0] = 0;
    __syncthreads();
    for (int off = 1; off < 256; off <<= 1) {
        int add = sh[t + 1] + ((t + 1 > off) ? sh[t + 1 - off] : 0);
        __syncthreads();
        sh[t + 1] = add;
        __syncthreads();
    }
    int base = bsum[b] + sh[t];
    int i0 = b * 1024 + t * 4;
    start[i0 + 0] = base;  base += v.x;
    start[i0 + 1] = base;  base += v.y;
    start[i0 + 2] = base;  base += v.z;
    start[i0 + 3] = base;
    if (b == SCNB - 1 && t == 255) start[NNP] = base + v.w;
}

// place row index into CSR slots (cols in R only; order within col arbitrary)
__global__ __launch_bounds__(256) void k_place(const int* __restrict__ row,
                                               const int* __restrict__ col,
                                               const unsigned* __restrict__ bR,
                                               const int* __restrict__ start,
                                               int* __restrict__ cur,
                                               int* __restrict__ el, int E) {
    int e = blockIdx.x * 256 + threadIdx.x;
    if (e >= E) return;
    int c = col[e];
    if (!((bR[c >> 5] >> (c & 31)) & 1u)) return;
    int pos = atomicAdd(&cur[c], 1);
    el[start[c] + pos] = row[e];
}

// ---------------------------------------------------------------------------
// gather1: g1[c] = dis[c] * sum dis[r]*x_raw[r];  sdeg[c] = dis[c]*sum dis[r].
// One wave per col; only cols in R (bitmap).  4-way ILP.
// ---------------------------------------------------------------------------
__global__ __launch_bounds__(256) void k_gather1(const int* __restrict__ el,
                                                 const int* __restrict__ start,
                                                 const float* __restrict__ dis,
                                                 const unsigned* __restrict__ filt,
                                                 const float* __restrict__ ut,
                                                 const float* __restrict__ itb,
                                                 float* __restrict__ g1,
                                                 float* __restrict__ sdeg) {
    int wid = (blockIdx.x * 256 + threadIdx.x) >> 6;
    int j = threadIdx.x & 63;
    if (wid >= NN) return;
    if (!((filt[wid >> 5] >> (wid & 31)) & 1u)) return;
    int s = start[wid], e = start[wid + 1];
    float a0 = 0.f, a1 = 0.f, a2 = 0.f, a3 = 0.f, sn = 0.f;
    int i = s;
    for (; i + 3 < e; i += 4) {
        int r0 = el[i], r1 = el[i + 1], r2 = el[i + 2], r3 = el[i + 3];
        float d0 = dis[r0], d1 = dis[r1], d2 = dis[r2], d3 = dis[r3];
        const float* p0 = (r0 < NU) ? ut + (size_t)r0 * 64 : itb + (size_t)(r0 - NU) * 64;
        const float* p1 = (r1 < NU) ? ut + (size_t)r1 * 64 : itb + (size_t)(r1 - NU) * 64;
        const float* p2 = (r2 < NU) ? ut + (size_t)r2 * 64 : itb + (size_t)(r2 - NU) * 64;
        const float* p3 = (r3 < NU) ? ut + (size_t)r3 * 64 : itb + (size_t)(r3 - NU) * 64;
        a0 = fmaf(d0, p0[j], a0);
        a1 = fmaf(d1, p1[j], a1);
        a2 = fmaf(d2, p2[j], a2);
        a3 = fmaf(d3, p3[j], a3);
        sn += (d0 + d1) + (d2 + d3);
    }
    for (; i < e; ++i) {
        int r0 = el[i];
        float d0 = dis[r0];
        const float* p0 = (r0 < NU) ? ut + (size_t)r0 * 64 : itb + (size_t)(r0 - NU) * 64;
        a0 = fmaf(d0, p0[j], a0);
        sn += d0;
    }
    float dc = dis[wid];
    g1[(size_t)wid * 64 + j] = dc * ((a0 + a1) + (a2 + a3));
    if (j == 0) sdeg[wid] = dc * sn;
}

// ---------------------------------------------------------------------------
// gather2: gg[c] = dis[c]*sum dis[r]*g1[r];  s2[c] = dis[c]*sum dis[r]*sdeg[r].
// cols in S.
// ---------------------------------------------------------------------------
__global__ __launch_bounds__(256) void k_gather2(const int* __restrict__ el,
                                                 const int* __restrict__ start,
                                                 const float* __restrict__ dis,
                                                 const unsigned* __restrict__ bS,
                                                 const float* __restrict__ g1,
                                                 const float* __restrict__ sdeg,
                                                 float* __restrict__ gg,
                                                 float* __restrict__ s2) {
    int wid = (blockIdx.x * 256 + threadIdx.x) >> 6;
    int j = threadIdx.x & 63;
    if (wid >= NN) return;
    if (!((bS[wid >> 5] >> (wid & 31)) & 1u)) return;
    int s = start[wid], e = start[wid + 1];
    float a0 = 0.f, a1 = 0.f, a2 = 0.f, a3 = 0.f, sa = 0.f;
    int i = s;
    for (; i + 3 < e; i += 4) {
        int r0 = el[i], r1 = el[i + 1], r2 = el[i + 2], r3 = el[i + 3];
        float d0 = dis[r0], d1 = dis[r1], d2 = dis[r2], d3 = dis[r3];
        a0 = fmaf(d0, g1[(size_t)r0 * 64 + j], a0);
        a1 = fmaf(d1, g1[(size_t)r1 * 64 + j], a1);
        a2 = fmaf(d2, g1[(size_t)r2 * 64 + j], a2);
        a3 = fmaf(d3, g1[(size_t)r3 * 64 + j], a3);
        sa = fmaf(d0, sdeg[r0], sa);
        sa = fmaf(d1, sdeg[r1], sa);
        sa = fmaf(d2, sdeg[r2], sa);
        sa = fmaf(d3, sdeg[r3], sa);
    }
    for (; i < e; ++i) {
        int r0 = el[i];
        float d0 = dis[r0];
        a0 = fmaf(d0, g1[(size_t)r0 * 64 + j], a0);
        sa = fmaf(d0, sdeg[r0], sa);
    }
    float dc = dis[wid];
    gg[(size_t)wid * 64 + j] = dc * ((a0 + a1) + (a2 + a3));
    if (j == 0) s2[wid] = dc * sa;
}

// ---------------------------------------------------------------------------
// k_fuse: W_va[l] = Wv[l] @ Wo[l];  b_va[l] = bv[l] @ Wo[l] + bo[l]
// ---------------------------------------------------------------------------
__global__ __launch_bounds__(256) void k_fuse(const float* __restrict__ qkvW,
                                              const float* __restrict__ qkvB,
                                              const float* __restrict__ outW,
                                              const float* __restrict__ outB,
                                              float* __restrict__ Wva,
                                              float* __restrict__ bva) {
    int l = blockIdx.x;
    __shared__ float wo[4096];
    int tid = threadIdx.x, j = tid & 63, kq = tid >> 6;
    for (int i = tid; i < 4096; i += 256) wo[i] = outW[l * 4096 + i];
    __syncthreads();
    for (int kk = 0; kk < 16; ++kk) {
        int k = kq * 16 + kk;
        float acc = 0.f;
        for (int m = 0; m < 64; ++m)
            acc = fmaf(qkvW[(size_t)l * 64 * 192 + k * 192 + 128 + m],
                       wo[m * 64 + j], acc);
        Wva[l * 4096 + k * 64 + j] = acc;
    }
    if (tid < 64) {
        float acc = outB[l * 64 + j];
        for (int m = 0; m < 64; ++m)
            acc = fmaf(qkvB[l * 192 + 128 + m], wo[m * 64 + j], acc);
        bva[l * 64 + j] = acc;
    }
}

// ---------------------------------------------------------------------------
// k_fuse2: Wff = W0@W1@corrW; bff = [b0@W1@corrW, b1@corrW, corrB]
// ---------------------------------------------------------------------------
__global__ __launch_bounds__(256) void k_fuse2(const float* __restrict__ glW,
                                               const float* __restrict__ glB,
                                               const float* __restrict__ corrW,
                                               const float* __restrict__ corrB,
                                               float* __restrict__ Wff,
                                               float* __restrict__ bff) {
    __shared__ float A[4096];   // W1
    __shared__ float B[4096];   // corrW
    __shared__ float T[4096];   // W0@W1
    __shared__ float vec[64];
    int tid = threadIdx.x, j = tid & 63, kq = tid >> 6;
    for (int i = tid; i < 4096; i += 256) { A[i] = glW[4096 + i]; B[i] = corrW[i]; }
    __syncthreads();
    for (int kk = 0; kk < 16; ++kk) {
        int k = kq * 16 + kk;
        float acc = 0.f;
        for (int m = 0; m < 64; ++m) acc = fmaf(glW[k * 64 + m], A[m * 64 + j], acc);
        T[k * 64 + j] = acc;
    }
    if (tid < 64) {
        float v = 0.f;
        for (int m = 0; m < 64; ++m) v = fmaf(glB[m], A[m * 64 + tid], v);
        vec[tid] = v;
    }
    __syncthreads();
    for (int kk = 0; kk < 16; ++kk) {
        int k = kq * 16 + kk;
        float acc = 0.f;
        for (int m = 0; m < 64; ++m) acc = fmaf(T[k * 64 + m], B[m * 64 + j], acc);
        Wff[k * 64 + j] = acc;
    }
    if (kq == 0) {
        float a = 0.f;
        for (int m = 0; m < 64; ++m) a = fmaf(vec[m], B[m * 64 + j], a);
        bff[j] = a;
    } else if (kq == 1) {
        float a = 0.f;
        for (int m = 0; m < 64; ++m) a = fmaf(glB[64 + m], B[m * 64 + j], a);
        bff[64 + j] = a;
    } else if (kq == 2) {
        bff[128 + j] = corrB[j];
    }
}

// ---------------------------------------------------------------------------
// k_wprep: transpose+convert FFN weights to bf16.
// ---------------------------------------------------------------------------
__global__ __launch_bounds__(256) void k_wprep(const float* __restrict__ ff1W,
                                               const float* __restrict__ ff2W,
                                               unsigned short* __restrict__ Wt1,
                                               unsigned short* __restrict__ Wt2) {
    __shared__ float sh[64][65];
    int b = blockIdx.x;          // 0..127
    int l = b >> 6, rem = b & 63;
    int mat = rem >> 5, tile = rem & 31;
    const float* src; unsigned short* dst; int C, R, r0, c0;
    if (mat == 0) { src = ff1W + (size_t)l * 64 * 2048; dst = Wt1 + (size_t)l * 2048 * 64;
                    R = 64; C = 2048; r0 = 0; c0 = tile * 64; }
    else          { src = ff2W + (size_t)l * 2048 * 64; dst = Wt2 + (size_t)l * 64 * 2048;
                    R = 2048; C = 64; r0 = tile * 64; c0 = 0; }
    int tid = threadIdx.x;
    for (int it = 0; it < 16; ++it) {
        int idx = it * 256 + tid;
        int lr = idx >> 6, lc = idx & 63;
        sh[lr][lc] = src[(size_t)(r0 + lr) * C + (c0 + lc)];
    }
    __syncthreads();
    for (int it = 0; it < 16; ++it) {
        int idx = it * 256 + tid;
        int lc = idx >> 6, lr = idx & 63;
        dst[(size_t)(c0 + lc) * R + (r0 + lr)] = f2bf(sh[lr][lc]);
    }
}

// ---------------------------------------------------------------------------
// k_proj: Cb[b] = gg[node]@Wff + s2[node]*bff1 + sdeg[node]*bff2 + corrB
// ---------------------------------------------------------------------------
__global__ __launch_bounds__(256) void k_proj(const float* __restrict__ gg,
                                              const float* __restrict__ sdeg,
                                              const float* __restrict__ s2,
                                              const int* __restrict__ users,
                                              const int* __restrict__ items,
                                              const float* __restrict__ Wff,
                                              const float* __restrict__ bff,
                                              float* __restrict__ Cb, int nb) {
    __shared__ float Ws[4096];
    __shared__ float xsh[16][64];
    __shared__ float ssh[16][2];
    int tid = threadIdx.x, j = tid & 63, rq = tid >> 6;
    for (int i = tid; i < 4096; i += 256) Ws[i] = Wff[i];
    int r0 = blockIdx.x * 16;
    for (int i = tid; i < 1024; i += 256) {
        int b = r0 + (i >> 6);
        int node = (b < nb) ? users[b] : (NU + items[b - nb]);
        xsh[i >> 6][i & 63] = gg[(size_t)node * 64 + (i & 63)];
    }
    if (tid < 16) {
        int b = r0 + tid;
        int node = (b < nb) ? users[b] : (NU + items[b - nb]);
        ssh[tid][0] = s2[node];
        ssh[tid][1] = sdeg[node];
    }
    __syncthreads();
    float b1j = bff[j], b2j = bff[64 + j], cbj = bff[128 + j];
    float acc[4];
#pragma unroll
    for (int i = 0; i < 4; ++i) acc[i] = cbj;
    for (int k = 0; k < 64; ++k) {
        float w = Ws[k * 64 + j];
#pragma unroll
        for (int i = 0; i < 4; ++i) acc[i] = fmaf(xsh[rq + 4 * i][k], w, acc[i]);
    }
#pragma unroll
    for (int i = 0; i < 4; ++i) {
        int r = rq + 4 * i;
        Cb[(size_t)(r0 + r) * 64 + j] = acc[i] + ssh[r][0] * b1j + ssh[r][1] * b2j;
    }
}

// ---------------------------------------------------------------------------
// k_attn: x = LN1(x + x @ W_va + b_va).  Writes fp32 Cb and bf16 xb.
// ---------------------------------------------------------------------------
__global__ __launch_bounds__(256) void k_attn(float* __restrict__ Cb,
                                              unsigned short* __restrict__ xb,
                                              const float* __restrict__ Wva,
                                              const float* __restrict__ bva,
                                              const float* __restrict__ g,
                                              const float* __restrict__ bt,
                                              int layer) {
    __shared__ float Ws[4096];
    __shared__ float xs[16][64];
    int tid = threadIdx.x, j = tid & 63, rq = tid >> 6;
    const float* wv = Wva + layer * 4096;
    for (int i = tid; i < 4096; i += 256) Ws[i] = wv[i];
    int row0 = blockIdx.x * 16;
    for (int i = tid; i < 1024; i += 256)
        xs[i >> 6][i & 63] = Cb[(size_t)(row0 + (i >> 6)) * 64 + (i & 63)];
    __syncthreads();
    float bv = bva[layer * 64 + j];
    float gg = g[layer * 64 + j], bb = bt[layer * 64 + j];
    float acc[4];
#pragma unroll
    for (int i = 0; i < 4; ++i) acc[i] = bv;
    for (int k = 0; k < 64; ++k) {
        float w = Ws[k * 64 + j];
#pragma unroll
        for (int i = 0; i < 4; ++i) acc[i] = fmaf(xs[rq * 4 + i][k], w, acc[i]);
    }
#pragma unroll
    for (int i = 0; i < 4; ++i) {
        int r = rq * 4 + i;
        float xv = xs[r][j] + acc[i];
        float s = xv;
#pragma unroll
        for (int o = 32; o >= 1; o >>= 1) s += __shfl_xor(s, o, 64);
        float m = s * (1.0f / 64.0f);
        float d = xv - m;
        float s2v = d * d;
#pragma unroll
        for (int o = 32; o >= 1; o >>= 1) s2v += __shfl_xor(s2v, o, 64);
        float xn = d * rsqrtf(s2v * (1.0f / 64.0f) + LNEPS) * gg + bb;
        Cb[(size_t)(row0 + r) * 64 + j] = xn;
        xb[(size_t)(row0 + r) * 64 + j] = f2bf(xn);
    }
}

// ---------------------------------------------------------------------------
// k_ffnm: full FFN via MFMA + fused residual + LN2.
// Phase 1 computes the TRANSPOSED t tile (MFMA operands swapped: D = W1f·xf,
// lane holds 4 consecutive h for one x-row) so the LDS store is one swizzled
// ds_write_b64 per fragment (was 16 scalar b16 writes).  Swap correctness:
// hw(loadM(A),loadM(B)) = A·B held for arbitrary inputs in prior rounds, so
// the same identity gives the transposed tile with operands exchanged.
// ---------------------------------------------------------------------------
__global__ __launch_bounds__(512) void k_ffnm(float* __restrict__ Cb,
                                              const unsigned short* __restrict__ xb,
                                              const unsigned short* __restrict__ Wt1,
                                              const unsigned short* __restrict__ Wt2,
                                              const float* __restrict__ ff1B,
                                              const float* __restrict__ ff2B,
                                              const float* __restrict__ g2,
                                              const float* __restrict__ b2t,
                                              int layer) {
    __shared__ short ts[2][32 * 128];   // bf16 t tiles, XOR-swizzled (16KB)
    __shared__ float ys[32 * 64];       // fp32 y (8KB)
    const unsigned short* w1 = Wt1 + (size_t)layer * 2048 * 64;
    const unsigned short* w2 = Wt2 + (size_t)layer * 64 * 2048;
    const float* b1 = ff1B + layer * 2048;
    int tid = threadIdx.x;
    int lane = tid & 63, wv = tid >> 6;
    int g = lane >> 4, r16 = lane & 15;
    int row0 = blockIdx.x * 32;
    int nt2 = wv & 3, mh = wv >> 2;

    bfx8 ax[2][2];
#pragma unroll
    for (int mt = 0; mt < 2; ++mt)
#pragma unroll
        for (int ks = 0; ks < 2; ++ks)
            ax[mt][ks] = *(const bfx8*)(xb + ((size_t)(row0 + 16 * mt + r16)) * 64
                                        + 32 * ks + 8 * g);

    f32x4 yfA = {0.f, 0.f, 0.f, 0.f}, yfB = {0.f, 0.f, 0.f, 0.f};
    int trow = 16 * mh + r16;

    for (int hc2 = 0; hc2 < 8; ++hc2) {
        bfx8 w2f[2][4];
#pragma unroll
        for (int sub = 0; sub < 2; ++sub)
#pragma unroll
            for (int ks2 = 0; ks2 < 4; ++ks2)
                w2f[sub][ks2] = *(const bfx8*)(w2 + ((size_t)(16 * nt2 + r16)) * 2048
                                               + (hc2 * 2 + sub) * 128
                                               + 32 * ks2 + 8 * g);
        // ---- phase 1 (swapped operands): lane -> t[xrow=r16(+16)][hb..hb+3]
#pragma unroll
        for (int sub = 0; sub < 2; ++sub) {
            int hbase = (hc2 * 2 + sub) * 128 + wv * 16;
            // bias per accumulator element (4 consecutive h at hbase+4g)
            f32x4 tf0 = *(const f32x4*)(b1 + hbase + 4 * g);
            f32x4 tf1 = tf0;
#pragma unroll
            for (int ks = 0; ks < 2; ++ks) {
                bfx8 bw = *(const bfx8*)(w1 + (size_t)(hbase + r16) * 64
                                         + 32 * ks + 8 * g);
                tf0 = MFMA16(bw, ax[0][ks], tf0);
                tf1 = MFMA16(bw, ax[1][ks], tf1);
            }
            int hb2 = (wv * 16 + 4 * g) * 2;     // byte offset within 128-col row
            short4 sv0, sv1;
            sv0.x = (short)f2bf(fmaxf(tf0[0], 0.f));
            sv0.y = (short)f2bf(fmaxf(tf0[1], 0.f));
            sv0.z = (short)f2bf(fmaxf(tf0[2], 0.f));
            sv0.w = (short)f2bf(fmaxf(tf0[3], 0.f));
            sv1.x = (short)f2bf(fmaxf(tf1[0], 0.f));
            sv1.y = (short)f2bf(fmaxf(tf1[1], 0.f));
            sv1.z = (short)f2bf(fmaxf(tf1[2], 0.f));
            sv1.w = (short)f2bf(fmaxf(tf1[3], 0.f));
            int rA = r16, rB = 16 + r16;
            int offA = (rA * 256 + hb2) ^ ((rA & 7) << 4);
            int offB = (rB * 256 + hb2) ^ ((rB & 7) << 4);
            *(short4*)((char*)ts[sub] + offA) = sv0;
            *(short4*)((char*)ts[sub] + offB) = sv1;
        }
        __syncthreads();
        // ---- phase 2: y[16*mh..][16*nt2..] += t @ W2c, both sub-chunks ----
#pragma unroll
        for (int sub = 0; sub < 2; ++sub)
#pragma unroll
            for (int ks2 = 0; ks2 < 4; ++ks2) {
                int kl = 32 * ks2 + 8 * g;
                int off2 = (trow * 256 + kl * 2) ^ ((trow & 7) << 4);
                bfx8 ta = *(const bfx8*)((char*)ts[sub] + off2);
                if (ks2 & 1) yfB = MFMA16(ta, w2f[sub][ks2], yfB);
                else         yfA = MFMA16(ta, w2f[sub][ks2], yfA);
            }
        __syncthreads();
    }
#pragma unroll
    for (int r = 0; r < 4; ++r)
        ys[(16 * mh + 4 * g + r) * 64 + 16 * nt2 + r16] = yfA[r] + yfB[r];
    __syncthreads();
    float b2 = ff2B[layer * 64 + lane];
    float gg = g2[layer * 64 + lane], bb = b2t[layer * 64 + lane];
#pragma unroll
    for (int i = 0; i < 4; ++i) {
        int r = wv * 4 + i;
        float xv = Cb[(size_t)(row0 + r) * 64 + lane] + ys[r * 64 + lane] + b2;
        float s = xv;
#pragma unroll
        for (int o = 32; o >= 1; o >>= 1) s += __shfl_xor(s, o, 64);
        float m = s * (1.0f / 64.0f);
        float d = xv - m;
        float s2v = d * d;
#pragma unroll
        for (int o = 32; o >= 1; o >>= 1) s2v += __shfl_xor(s2v, o, 64);
        float xn = d * rsqrtf(s2v * (1.0f / 64.0f) + LNEPS) * gg + bb;
        Cb[(size_t)(row0 + r) * 64 + lane] = xn;
    }
}

// out[b] = dot(user_row b, item_row nb+b); quarter-wave per b.
__global__ __launch_bounds__(256) void k_dot(const float* __restrict__ Cb,
                                             float* __restrict__ out, int nb) {
    int t = blockIdx.x * 256 + threadIdx.x;
    int b = t >> 4;
    if (b >= nb) return;
    int q = (t & 15) * 4;
    const float4 u = *reinterpret_cast<const float4*>(Cb + (size_t)b * 64 + q);
    const float4 v = *reinterpret_cast<const float4*>(Cb + (size_t)(nb + b) * 64 + q);
    float s = u.x * v.x + u.y * v.y + u.z * v.z + u.w * v.w;
#pragma unroll
    for (int o = 8; o >= 1; o >>= 1) s += __shfl_xor(s, o, 16);
    if ((t & 15) == 0) out[b] = s;
}

extern "C" void kernel_launch(void* const* d_in, const int* in_sizes, int n_in,
                              void* d_out, int out_size, void* d_ws, size_t ws_size,
                              hipStream_t stream) {
    const int* users = (const int*)d_in[0];
    const int* items = (const int*)d_in[1];
    const int* ei    = (const int*)d_in[2];
    const float* ut  = (const float*)d_in[3];
    const float* itb = (const float*)d_in[4];
    const float* glW = (const float*)d_in[5];
    const float* glB = (const float*)d_in[6];
    const float* corrW = (const float*)d_in[7];
    const float* corrB = (const float*)d_in[8];
    const float* qkvW = (const float*)d_in[9];
    const float* qkvB = (const float*)d_in[10];
    const float* outW = (const float*)d_in[11];
    const float* outB = (const float*)d_in[12];
    const float* ff1W = (const float*)d_in[13];
    const float* ff1B = (const float*)d_in[14];
    const float* ff2W = (const float*)d_in[15];
    const float* ff2B = (const float*)d_in[16];
    const float* ln1g = (const float*)d_in[17];
    const float* ln1b = (const float*)d_in[18];
    const float* ln2g = (const float*)d_in[19];
    const float* ln2b = (const float*)d_in[20];

    const int E  = in_sizes[2] / 2;      // 1,750,000
    const int nb = in_sizes[0];          // 4096
    const int nrows = 2 * nb;            // 8192
    const int* rowp = ei;
    const int* colp = ei + E;

    // workspace carve-up (~92 MB)
    char* w = (char*)d_ws;
    size_t off = 0;
    auto alloc = [&](size_t bytes) {
        char* p = w + off;
        off += (bytes + 255) & ~(size_t)255;
        return p;
    };
    // zeroed region (contiguous -> single memset): deg, cnt, cur, bS, bR
    size_t zero0 = off;
    int*      deg   = (int*)alloc((size_t)NN * 4);
    int*      cnt   = (int*)alloc((size_t)NNP * 4);
    int*      cur   = (int*)alloc((size_t)NN * 4);
    unsigned* bS    = (unsigned*)alloc((NNP / 32) * 4);
    unsigned* bR    = (unsigned*)alloc((NNP / 32) * 4);
    size_t zlen = off - zero0;
    float*    dis   = (float*)alloc((size_t)NN * 4);
    int*      start = (int*)alloc((size_t)(NNP + 1) * 4);
    int*      bsum  = (int*)alloc((size_t)SCNB * 4);
    int*      el    = (int*)alloc((size_t)E * 4);
    float*    bufA  = (float*)alloc((size_t)NN * 64 * 4);   // g1 (38.4 MB)
    float*    bufB  = (float*)alloc((size_t)NN * 64 * 4);   // gg
    float*    sdeg  = (float*)alloc((size_t)NN * 4);
    float*    s2    = (float*)alloc((size_t)NN * 4);
    float*    cb    = (float*)alloc((size_t)nrows * 64 * 4);
    float*    Wva   = (float*)alloc(2 * 4096 * 4);
    float*    bva   = (float*)alloc(2 * 64 * 4);
    float*    Wff   = (float*)alloc(4096 * 4);
    float*    bff   = (float*)alloc(192 * 4);
    unsigned short* xbb = (unsigned short*)alloc((size_t)nrows * 64 * 2);
    unsigned short* Wt1 = (unsigned short*)alloc((size_t)2 * 2048 * 64 * 2);
    unsigned short* Wt2 = (unsigned short*)alloc((size_t)2 * 64 * 2048 * 2);
    float*    outp  = (float*)d_out;

    hipMemsetAsync(w + zero0, 0, zlen, stream);

    int eb = (E + 255) / 256;
    int nnb = (NN + 255) / 256;

    // --- CSR build (filtered global-atomic structure; round-7 proven) ---
    k_markS<<<(2 * nb + 255) / 256, 256, 0, stream>>>(users, items, bS, nb);
    k_pre1<<<eb, 256, 0, stream>>>(rowp, colp, bS, deg, bR, E);
    k_dis<<<nnb, 256, 0, stream>>>(deg, dis);
    k_cnt<<<eb, 256, 0, stream>>>(colp, bR, cnt, E);
    k_scan1<<<SCNB, 256, 0, stream>>>(cnt, bsum);
    k_scan2<<<1, 256, 0, stream>>>(bsum, SCNB);
    k_scan3<<<SCNB, 256, 0, stream>>>(cnt, bsum, start);
    k_place<<<eb, 256, 0, stream>>>(rowp, colp, bR, start, cur, el, E);
    k_fuse<<<2, 256, 0, stream>>>(qkvW, qkvB, outW, outB, Wva, bva);
    k_fuse2<<<1, 256, 0, stream>>>(glW, glB, corrW, corrB, Wff, bff);
    k_wprep<<<128, 256, 0, stream>>>(ff1W, ff2W, Wt1, Wt2);

    int agb = (NN + 3) / 4;    // 4 waves/block, 1 wave per col

    // commuted GCN: gather raw tables (R cols), gather again (S cols),
    // then one fused 8K-row projection
    k_gather1<<<agb, 256, 0, stream>>>(el, start, dis, bR, ut, itb, bufA, sdeg);
    k_gather2<<<agb, 256, 0, stream>>>(el, start, dis, bS, bufA, sdeg, bufB, s2);
    k_proj<<<(nrows + 15) / 16, 256, 0, stream>>>(bufB, sdeg, s2, users, items,
                                                  Wff, bff, cb, nb);

    // transformer: per layer  attn+LN1 (emits bf16 x) -> MFMA FFN + LN2
    for (int l = 0; l < 2; ++l) {
        k_attn<<<nrows / 16, 256, 0, stream>>>(cb, xbb, Wva, bva, ln1g, ln1b, l);
        k_ffnm<<<nrows / 32, 512, 0, stream>>>(cb, xbb, Wt1, Wt2, ff1B, ff2B,
                                               ln2g, ln2b, l);
    }
    k_dot<<<(nb * 16 + 255) / 256, 256, 0, stream>>>(cb, outp, nb);
}